// Round 3
// baseline (19053.281 us; speedup 1.0000x reference)
//
#include <hip/hip_runtime.h>
#include <hip/hip_bf16.h>

// Shapes (fixed by the problem)
#define BATCH 256
#define ENCH  512   // encoder hidden (e)
#define WWID  256   // encoder width  (w)
#define ATT   256   // attn size      (a)
#define DECH  256   // decoder hidden (d)
#define EMBD  128
#define VOC   81
#define TT    100

// ---------- numerics: fp32, libm-grade (trajectory must match np fp32 ref) ----
__device__ __forceinline__ float ftanh(float x) {
  float e = expf(2.0f * x);
  return 1.0f - 2.0f / (e + 1.0f);
}
__device__ __forceinline__ float fsig(float x) {
  return 1.0f / (1.0f + expf(-x));
}

// ---------------- init: zero h, c, hbuf; x=sos; barrier counter=0 ------------
__global__ void k_init(float* __restrict__ cbuf, float* __restrict__ xkT0_h,
                       float* __restrict__ hbuf, int* __restrict__ xbuf,
                       unsigned* __restrict__ cnt, const int* __restrict__ sos) {
  int idx = blockIdx.x * 256 + threadIdx.x;
  if (blockIdx.x < 256) {
    cbuf[idx] = 0.0f;
    xkT0_h[idx] = 0.0f;
    hbuf[idx] = 0.0f;
  } else {
    xbuf[threadIdx.x] = sos[0];
    if (threadIdx.x == 0) *cnt = 0u;
  }
}

// ------------- build transposed weights: W2[k][col], DW2[k][a] ---------------
// W2 rows 0..511 = w_ih ctx part, 512..767 = w_hh; columns gate-interleaved:
// col = (j>>4)*64 + gate*16 + (j&15)  so each jt-block reads 256B/row.
__global__ void k_build(const float* __restrict__ w_ih, const float* __restrict__ w_hh,
                        const float* __restrict__ dlw,
                        float* __restrict__ W2, float* __restrict__ DW2) {
  int k = blockIdx.x, tid = threadIdx.x;
  if (k < 768) {
    for (int g = tid; g < 1024; g += 256) {
      int gate = g >> 8, j = g & 255;
      int nc = ((j >> 4) << 6) + (gate << 4) + (j & 15);
      W2[(size_t)k * 1024 + nc] = (k < 512) ? w_ih[(size_t)g * 640 + 128 + k]
                                            : w_hh[(size_t)g * 256 + (k - 512)];
    }
  } else {
    int kk = k - 768;
    DW2[kk * 256 + tid] = dlw[tid * 256 + kk];
  }
}

// ---------- emb_gates[v][col] = b_ih+b_hh + emb@w_ih  (same permuted cols) ---
__global__ void k_embg(const float* __restrict__ emb, const float* __restrict__ w_ih,
                       const float* __restrict__ b_ih, const float* __restrict__ b_hh,
                       float* __restrict__ embg) {
  int v = blockIdx.x, tid = threadIdx.x;
  __shared__ float em[EMBD];
  if (tid < EMBD) em[tid] = emb[v * EMBD + tid];
  __syncthreads();
  for (int g = tid; g < 1024; g += 256) {
    float s = b_ih[g] + b_hh[g];
    const float* wr = w_ih + (size_t)g * 640;
#pragma unroll 8
    for (int e = 0; e < EMBD; ++e) s += em[e] * wr[e];
    int gate = g >> 8, j = g & 255;
    int nc = ((j >> 4) << 6) + (gate << 4) + (j & 15);
    embg[v * 1024 + nc] = s;
  }
}

// ------------- weighted_enc[b][a][w] = sum_e cw[a][e] enc[b][e][w] + cb[a] ----
__global__ void __launch_bounds__(256) k_we(const float* __restrict__ enc,
                                            const float* __restrict__ cw,
                                            const float* __restrict__ cb,
                                            float* __restrict__ we) {
  int bid = blockIdx.x;
  int b = bid >> 4, at = (bid >> 2) & 3, wt = bid & 3;
  int a0 = at * 64, w0 = wt * 64;
  __shared__ float cwT[32][68];
  __shared__ float encT[32][64];
  int tid = threadIdx.x;
  int tx = tid & 15, ty = tid >> 4;
  float acc[4][4] = {};
  const float* encB = enc + (size_t)b * ENCH * WWID;
  for (int k0 = 0; k0 < ENCH; k0 += 32) {
    {
      int a = tid >> 2, e8 = (tid & 3) * 8;
      const float* src = cw + (size_t)(a0 + a) * ENCH + k0 + e8;
      float4 v0 = *(const float4*)(src);
      float4 v1 = *(const float4*)(src + 4);
      cwT[e8 + 0][a] = v0.x; cwT[e8 + 1][a] = v0.y; cwT[e8 + 2][a] = v0.z; cwT[e8 + 3][a] = v0.w;
      cwT[e8 + 4][a] = v1.x; cwT[e8 + 5][a] = v1.y; cwT[e8 + 6][a] = v1.z; cwT[e8 + 7][a] = v1.w;
    }
    {
      int e = tid >> 3, w8 = (tid & 7) * 8;
      const float* src = encB + (size_t)(k0 + e) * WWID + w0 + w8;
      *(float4*)&encT[e][w8] = *(const float4*)src;
      *(float4*)&encT[e][w8 + 4] = *(const float4*)(src + 4);
    }
    __syncthreads();
#pragma unroll
    for (int e = 0; e < 32; ++e) {
      float4 av = *(const float4*)&cwT[e][ty * 4];
      float4 bv = *(const float4*)&encT[e][tx * 4];
      float a4[4] = {av.x, av.y, av.z, av.w};
      float b4[4] = {bv.x, bv.y, bv.z, bv.w};
#pragma unroll
      for (int i = 0; i < 4; ++i)
#pragma unroll
        for (int j = 0; j < 4; ++j) acc[i][j] += a4[i] * b4[j];
    }
    __syncthreads();
  }
#pragma unroll
  for (int i = 0; i < 4; ++i) {
    int a = a0 + ty * 4 + i;
    float bias = cb[a];
    float4 o;
    o.x = acc[i][0] + bias; o.y = acc[i][1] + bias;
    o.z = acc[i][2] + bias; o.w = acc[i][3] + bias;
    *(float4*)(we + ((size_t)(b * ATT + a)) * WWID + w0 + tx * 4) = o;
  }
}

// ---------------- grid barrier (monotonic epoch, device scope) ---------------
__device__ __forceinline__ void gbar(unsigned* cnt, unsigned target) {
  __syncthreads();
  if (threadIdx.x == 0) {
    __threadfence();                 // release: push our writes device-wide
    atomicAdd(cnt, 1u);
    while (__hip_atomic_load(cnt, __ATOMIC_ACQUIRE, __HIP_MEMORY_SCOPE_AGENT) < target) {
      __builtin_amdgcn_s_sleep(2);
    }
  }
  __syncthreads();
  __threadfence();                   // acquire: invalidate stale cached lines
}

// =================== persistent kernel: all 100 steps ========================
// grid 256 x 512 (8 waves/CU, all blocks co-resident; capacity = 4 blocks/CU)
__global__ void __launch_bounds__(512, 1) k_loop(
    const float* __restrict__ we, const float* __restrict__ enc,
    const float* __restrict__ W2, const float* __restrict__ DW2,
    const float* __restrict__ embg, const float* __restrict__ dlb,
    const float* __restrict__ ew, const float* __restrict__ eb,
    const float* __restrict__ ow, const float* __restrict__ ob,
    float* __restrict__ xkT0, float* __restrict__ xkT1,
    float* __restrict__ cbuf, float* __restrict__ hbuf,
    int* __restrict__ xbuf, unsigned* __restrict__ cnt,
    float* __restrict__ out) {
  const int tid = threadIdx.x;
  const int b = blockIdx.x;                       // phase A / C batch
  const int bt = blockIdx.x >> 4, jt = blockIdx.x & 15;  // phase B tile
  const int b0 = bt << 4;

  __shared__ float dp_s[256], ew_s[256], sc_s[256], h_s[256];
  __shared__ float partA[8][64][4];
  __shared__ float partB[8][64][17];
  __shared__ float red[8];
  __shared__ int x_s[16];
  __shared__ float lg[VOC], lp_s[VOC];

  if (tid < 256) {
    ew_s[tid] = ew[tid];
    h_s[tid] = hbuf[b * 256 + tid];   // zeros at t=0 (k_init)
  }
  const float ebv = eb[0];
  unsigned ep = 0;

  for (int t = 0; t < TT; ++t) {
    float* xc = (t & 1) ? xkT1 : xkT0;   // ctx(t) rows 0..511, h(t-1) rows 512..767
    float* xn = (t & 1) ? xkT0 : xkT1;   // h(t) written to rows 512..767

    // ---------------- Phase A: dp + attention + softmax + context ------------
    __syncthreads();
    if (tid < 256) {
      float acc = dlb[tid];
      const float* dw = DW2 + tid;
#pragma unroll 8
      for (int k = 0; k < DECH; ++k) acc += dw[k * 256] * h_s[k];
      dp_s[tid] = acc;
    }
    __syncthreads();
    {
      int q = tid & 63, pt = tid >> 6;
      const float* weB = we + ((size_t)b << 16);
      float s0 = 0, s1 = 0, s2 = 0, s3 = 0;
      int abase = pt * 32;
#pragma unroll 4
      for (int i = 0; i < 32; ++i) {
        int aa = abase + i;
        float4 wv = *(const float4*)(weB + (size_t)aa * 256 + q * 4);
        float d = dp_s[aa], w8 = ew_s[aa];
        s0 += w8 * ftanh(wv.x + d);
        s1 += w8 * ftanh(wv.y + d);
        s2 += w8 * ftanh(wv.z + d);
        s3 += w8 * ftanh(wv.w + d);
      }
      partA[pt][q][0] = s0; partA[pt][q][1] = s1;
      partA[pt][q][2] = s2; partA[pt][q][3] = s3;
    }
    __syncthreads();
    float sv = 0.0f;
    if (tid < 256) {
      sv = ebv;
#pragma unroll
      for (int p = 0; p < 8; ++p) sv += partA[p][tid >> 2][tid & 3];
      float mm = sv;
      for (int off = 32; off; off >>= 1) mm = fmaxf(mm, __shfl_xor(mm, off));
      if ((tid & 63) == 0) red[tid >> 6] = mm;
    }
    __syncthreads();
    float mA = fmaxf(fmaxf(red[0], red[1]), fmaxf(red[2], red[3]));
    float pa = 0.0f;
    if (tid < 256) {
      pa = expf(sv - mA);
      float ss = pa;
      for (int off = 32; off; off >>= 1) ss += __shfl_xor(ss, off);
      if ((tid & 63) == 0) red[4 + (tid >> 6)] = ss;
    }
    __syncthreads();
    {
      float S = red[4] + red[5] + red[6] + red[7];
      if (tid < 256) {
        float alpha = pa / S;
        sc_s[tid] = alpha;
        out[(size_t)(BATCH * TT * VOC) + (size_t)(BATCH * TT) +
            ((size_t)b * TT + t) * WWID + tid] = alpha;
      }
    }
    __syncthreads();
    {
      int lane = tid & 63, wvi = tid >> 6;
      const float* encB = enc + (size_t)b * ENCH * WWID;
      float4 al = *(const float4*)&sc_s[lane * 4];
#pragma unroll 2
      for (int e = wvi; e < ENCH; e += 8) {
        float4 evv = *(const float4*)(encB + (size_t)e * WWID + lane * 4);
        float s = evv.x * al.x + evv.y * al.y + evv.z * al.z + evv.w * al.w;
        for (int off = 32; off; off >>= 1) s += __shfl_xor(s, off);
        if (lane == 0) xc[(size_t)e * 256 + b] = s;  // ctx rows of current buf
      }
    }
    ++ep; gbar(cnt, ep * 256u);

    // ---------------- Phase B: gates GEMM (K=768, ks 8x96) + LSTM ------------
    {
      if (tid < 16) x_s[tid] = xbuf[b0 + tid];
      int ks = tid >> 6, r = tid & 63;
      int col = (jt << 6) + r;
      float acc[16] = {};
      int k0 = ks * 96;
      for (int k = k0; k < k0 + 96; ++k) {
        float wv = W2[(size_t)k * 1024 + col];
        const float* xr = xc + (size_t)k * 256 + b0;
#pragma unroll
        for (int bi = 0; bi < 16; ++bi) acc[bi] += wv * xr[bi];
      }
#pragma unroll
      for (int bi = 0; bi < 16; ++bi) partB[ks][r][bi] = acc[bi];
    }
    __syncthreads();
    if (tid < 256) {
      int bb = tid >> 4, jj = tid & 15;
      float g4[4];
#pragma unroll
      for (int g = 0; g < 4; ++g) {
        int rr = (g << 4) + jj;
        float s = 0.0f;
#pragma unroll
        for (int p = 0; p < 8; ++p) s += partB[p][rr][bb];
        g4[g] = s;
      }
      const float* er = embg + (size_t)x_s[bb] * 1024 + (jt << 6) + jj;
      float iv = fsig(g4[0] + er[0]);
      float fv = fsig(g4[1] + er[16]);
      float gv = ftanh(g4[2] + er[32]);
      float ov = fsig(g4[3] + er[48]);
      int gb = b0 + bb, j = (jt << 4) + jj;
      int cidx = gb * 256 + j;
      float cn = fv * cbuf[cidx] + iv * gv;
      float hn = ov * ftanh(cn);
      cbuf[cidx] = cn;
      hbuf[cidx] = hn;
      xn[(size_t)(512 + j) * 256 + gb] = hn;
    }
    ++ep; gbar(cnt, ep * 256u);

    // ---------------- Phase C: logits + log_softmax + argmax -----------------
    if (tid < 256) h_s[tid] = hbuf[b * 256 + tid];  // h(t); stays live for A(t+1)
    __syncthreads();
    {
      int lane = tid & 63, wv = tid >> 6;
      float4 hh = *(const float4*)&h_s[lane * 4];
      for (int v = wv; v < VOC; v += 8) {
        float4 wr = *(const float4*)(ow + (size_t)v * 256 + lane * 4);
        float s = wr.x * hh.x + wr.y * hh.y + wr.z * hh.z + wr.w * hh.w;
        for (int off = 32; off; off >>= 1) s += __shfl_xor(s, off);
        if (lane == 0) lg[v] = s + ob[v];
      }
    }
    __syncthreads();
    float v_ = -3.402823e38f, pe = 0.0f;
    if (tid < 256) {
      v_ = (tid < VOC) ? lg[tid] : -3.402823e38f;
      float mm = v_;
      for (int off = 32; off; off >>= 1) mm = fmaxf(mm, __shfl_xor(mm, off));
      if ((tid & 63) == 0) red[tid >> 6] = mm;
    }
    __syncthreads();
    float mC = fmaxf(fmaxf(red[0], red[1]), fmaxf(red[2], red[3]));
    if (tid < 256) {
      pe = (tid < VOC) ? expf(v_ - mC) : 0.0f;
      float ss = pe;
      for (int off = 32; off; off >>= 1) ss += __shfl_xor(ss, off);
      if ((tid & 63) == 0) red[4 + (tid >> 6)] = ss;
    }
    __syncthreads();
    {
      float S = red[4] + red[5] + red[6] + red[7];
      float lse = mC + logf(S);
      if (tid < VOC) {
        float lp = v_ - lse;
        lp_s[tid] = lp;
        out[((size_t)b * TT + t) * VOC + tid] = lp;
      }
    }
    __syncthreads();
    if (tid == 0) {
      int best = 0;
      float bv = lp_s[0];
      for (int v = 1; v < VOC; ++v) {
        float x = lp_s[v];
        if (x > bv) { bv = x; best = v; }
      }
      xbuf[b] = best;
      out[(size_t)(BATCH * TT * VOC) + (size_t)b * TT + t] = (float)best;
    }
    // no barrier here: xbuf(t) is read by B(t+1) only after the A(t+1) barrier
  }
}

extern "C" void kernel_launch(void* const* d_in, const int* in_sizes, int n_in,
                              void* d_out, int out_size, void* d_ws, size_t ws_size,
                              hipStream_t stream) {
  (void)in_sizes; (void)n_in; (void)out_size; (void)ws_size;
  const float* enc = (const float*)d_in[0];
  const float* emb = (const float*)d_in[1];
  const float* ecw = (const float*)d_in[2];
  const float* ecb = (const float*)d_in[3];
  const float* dlw = (const float*)d_in[4];
  const float* dlb = (const float*)d_in[5];
  const float* ew  = (const float*)d_in[6];
  const float* eb  = (const float*)d_in[7];
  const float* wih = (const float*)d_in[8];
  const float* whh = (const float*)d_in[9];
  const float* bih = (const float*)d_in[10];
  const float* bhh = (const float*)d_in[11];
  const float* ow  = (const float*)d_in[12];
  const float* ob  = (const float*)d_in[13];
  const int* sos   = (const int*)d_in[15];
  float* out = (float*)d_out;
  float* ws = (float*)d_ws;

  // workspace map (floats)
  size_t off = 0;
  float* we    = ws + off; off += (size_t)BATCH * ATT * WWID;  // 16,777,216
  float* W2    = ws + off; off += (size_t)768 * 1024;
  float* DW2   = ws + off; off += (size_t)256 * 256;
  float* embg  = ws + off; off += (size_t)VOC * 1024;
  off = (off + 255) & ~(size_t)255;
  float* xkT0  = ws + off; off += (size_t)768 * 256;  // rows 0..511 ctx, 512..767 h
  float* xkT1  = ws + off; off += (size_t)768 * 256;
  float* cbuf  = ws + off; off += (size_t)256 * 256;
  float* hbuf  = ws + off; off += (size_t)256 * 256;
  int* xbuf    = (int*)(ws + off); off += 256;
  unsigned* cnt = (unsigned*)(ws + off); off += 64;

  k_init<<<257, 256, 0, stream>>>(cbuf, xkT0 + (size_t)512 * 256, hbuf, xbuf, cnt, sos);
  k_build<<<1024, 256, 0, stream>>>(wih, whh, dlw, W2, DW2);
  k_embg<<<VOC, 256, 0, stream>>>(emb, wih, bih, bhh, embg);
  k_we<<<4096, 256, 0, stream>>>(enc, ecw, ecb, we);
  k_loop<<<256, 512, 0, stream>>>(we, enc, W2, DW2, embg, dlb, ew, eb, ow, ob,
                                  xkT0, xkT1, cbuf, hbuf, xbuf, cnt, out);
}

// Round 4
// 11874.806 us; speedup vs baseline: 1.6045x; 1.6045x over previous
//
#include <hip/hip_runtime.h>
#include <hip/hip_bf16.h>

// Shapes (fixed by the problem)
#define BATCH 256
#define ENCH  512   // encoder hidden (e)
#define WWID  256   // encoder width  (w)
#define ATT   256   // attn size      (a)
#define DECH  256   // decoder hidden (d)
#define EMBD  128
#define VOC   81
#define TT    100

#define AGENT __HIP_MEMORY_SCOPE_AGENT
#define RLX   __ATOMIC_RELAXED

// ---------- numerics: fp32, libm-grade (trajectory must match np fp32 ref) ----
__device__ __forceinline__ float ftanh(float x) {
  float e = expf(2.0f * x);
  return 1.0f - 2.0f / (e + 1.0f);
}
__device__ __forceinline__ float fsig(float x) {
  return 1.0f / (1.0f + expf(-x));
}

// ---------------- init: zero h, c, hbuf; x=sos; barrier counter=0 ------------
__global__ void k_init(float* __restrict__ cbuf, float* __restrict__ xkT0_h,
                       float* __restrict__ hbuf, int* __restrict__ xbuf,
                       unsigned* __restrict__ cnt, const int* __restrict__ sos) {
  int idx = blockIdx.x * 256 + threadIdx.x;
  if (blockIdx.x < 256) {
    cbuf[idx] = 0.0f;
    xkT0_h[idx] = 0.0f;
    hbuf[idx] = 0.0f;
  } else {
    xbuf[threadIdx.x] = sos[0];
    if (threadIdx.x == 0) *cnt = 0u;
  }
}

// ------------- build transposed weights: W2[k][col], DW2[k][a] ---------------
// W2 rows 0..511 = w_ih ctx part, 512..767 = w_hh; columns gate-interleaved:
// col = (j>>4)*64 + gate*16 + (j&15)  so each jt-block reads 256B/row.
__global__ void k_build(const float* __restrict__ w_ih, const float* __restrict__ w_hh,
                        const float* __restrict__ dlw,
                        float* __restrict__ W2, float* __restrict__ DW2) {
  int k = blockIdx.x, tid = threadIdx.x;
  if (k < 768) {
    for (int g = tid; g < 1024; g += 256) {
      int gate = g >> 8, j = g & 255;
      int nc = ((j >> 4) << 6) + (gate << 4) + (j & 15);
      W2[(size_t)k * 1024 + nc] = (k < 512) ? w_ih[(size_t)g * 640 + 128 + k]
                                            : w_hh[(size_t)g * 256 + (k - 512)];
    }
  } else {
    int kk = k - 768;
    DW2[kk * 256 + tid] = dlw[tid * 256 + kk];
  }
}

// ---------- emb_gates[v][col] = b_ih+b_hh + emb@w_ih  (same permuted cols) ---
__global__ void k_embg(const float* __restrict__ emb, const float* __restrict__ w_ih,
                       const float* __restrict__ b_ih, const float* __restrict__ b_hh,
                       float* __restrict__ embg) {
  int v = blockIdx.x, tid = threadIdx.x;
  __shared__ float em[EMBD];
  if (tid < EMBD) em[tid] = emb[v * EMBD + tid];
  __syncthreads();
  for (int g = tid; g < 1024; g += 256) {
    float s = b_ih[g] + b_hh[g];
    const float* wr = w_ih + (size_t)g * 640;
#pragma unroll 8
    for (int e = 0; e < EMBD; ++e) s += em[e] * wr[e];
    int gate = g >> 8, j = g & 255;
    int nc = ((j >> 4) << 6) + (gate << 4) + (j & 15);
    embg[v * 1024 + nc] = s;
  }
}

// ------------- weighted_enc[b][a][w] = sum_e cw[a][e] enc[b][e][w] + cb[a] ----
__global__ void __launch_bounds__(256) k_we(const float* __restrict__ enc,
                                            const float* __restrict__ cw,
                                            const float* __restrict__ cb,
                                            float* __restrict__ we) {
  int bid = blockIdx.x;
  int b = bid >> 4, at = (bid >> 2) & 3, wt = bid & 3;
  int a0 = at * 64, w0 = wt * 64;
  __shared__ float cwT[32][68];
  __shared__ float encT[32][64];
  int tid = threadIdx.x;
  int tx = tid & 15, ty = tid >> 4;
  float acc[4][4] = {};
  const float* encB = enc + (size_t)b * ENCH * WWID;
  for (int k0 = 0; k0 < ENCH; k0 += 32) {
    {
      int a = tid >> 2, e8 = (tid & 3) * 8;
      const float* src = cw + (size_t)(a0 + a) * ENCH + k0 + e8;
      float4 v0 = *(const float4*)(src);
      float4 v1 = *(const float4*)(src + 4);
      cwT[e8 + 0][a] = v0.x; cwT[e8 + 1][a] = v0.y; cwT[e8 + 2][a] = v0.z; cwT[e8 + 3][a] = v0.w;
      cwT[e8 + 4][a] = v1.x; cwT[e8 + 5][a] = v1.y; cwT[e8 + 6][a] = v1.z; cwT[e8 + 7][a] = v1.w;
    }
    {
      int e = tid >> 3, w8 = (tid & 7) * 8;
      const float* src = encB + (size_t)(k0 + e) * WWID + w0 + w8;
      *(float4*)&encT[e][w8] = *(const float4*)src;
      *(float4*)&encT[e][w8 + 4] = *(const float4*)(src + 4);
    }
    __syncthreads();
#pragma unroll
    for (int e = 0; e < 32; ++e) {
      float4 av = *(const float4*)&cwT[e][ty * 4];
      float4 bv = *(const float4*)&encT[e][tx * 4];
      float a4[4] = {av.x, av.y, av.z, av.w};
      float b4[4] = {bv.x, bv.y, bv.z, bv.w};
#pragma unroll
      for (int i = 0; i < 4; ++i)
#pragma unroll
        for (int j = 0; j < 4; ++j) acc[i][j] += a4[i] * b4[j];
    }
    __syncthreads();
  }
#pragma unroll
  for (int i = 0; i < 4; ++i) {
    int a = a0 + ty * 4 + i;
    float bias = cb[a];
    float4 o;
    o.x = acc[i][0] + bias; o.y = acc[i][1] + bias;
    o.z = acc[i][2] + bias; o.w = acc[i][3] + bias;
    *(float4*)(we + ((size_t)(b * ATT + a)) * WWID + w0 + tx * 4) = o;
  }
}

// ------ grid barrier: NO cache-invalidating fences (data goes via atomics) ---
// __syncthreads drains each wave's vmcnt (compiler emits s_waitcnt before
// s_barrier), so all this block's agent-scope atomic stores are visible at the
// coherence point before lane 0 increments. Readers use agent-scope atomic
// loads, so no acquire-invalidate is needed -> L2 keeps we/enc/W2 hot.
__device__ __forceinline__ void gbar(unsigned* cnt, unsigned target) {
  __syncthreads();
  if (threadIdx.x == 0) {
    asm volatile("s_waitcnt vmcnt(0)" ::: "memory");
    __hip_atomic_fetch_add(cnt, 1u, RLX, AGENT);
    while (__hip_atomic_load(cnt, RLX, AGENT) < target) {
      __builtin_amdgcn_s_sleep(2);
    }
  }
  __syncthreads();
}

// =================== persistent kernel: all 100 steps ========================
// grid 256 x 512 (1 block/CU, 8 waves; all blocks co-resident)
__global__ void __launch_bounds__(512, 1) k_loop(
    const float* __restrict__ we, const float* __restrict__ enc,
    const float* __restrict__ W2, const float* __restrict__ DW2,
    const float* __restrict__ embg, const float* __restrict__ dlb,
    const float* __restrict__ ew, const float* __restrict__ eb,
    const float* __restrict__ ow, const float* __restrict__ ob,
    float* __restrict__ xkT0, float* __restrict__ xkT1,
    float* __restrict__ cbuf, float* __restrict__ hbuf,
    int* __restrict__ xbuf, unsigned* __restrict__ cnt,
    float* __restrict__ out) {
  const int tid = threadIdx.x;
  const int b = blockIdx.x;                              // phase A / C batch
  const int bt = blockIdx.x >> 4, jt = blockIdx.x & 15;  // phase B tile
  const int b0 = bt << 4;

  // blob unions: partA[8][64][4] (A) | x_lds[768][16] then partB[8][64][17] (B)
  __shared__ float blob[12288];  // 48 KB
  __shared__ float dp_s[256], ew_s[256], sc_s[256], h_s[256];
  __shared__ float red[8];
  __shared__ int x_s[16];
  __shared__ float lg[VOC], lp_s[VOC];

  float (*partA)[64][4] = (float (*)[64][4])blob;
  float (*partB)[64][17] = (float (*)[64][17])blob;

  if (tid < 256) {
    ew_s[tid] = ew[tid];
    h_s[tid] = 0.0f;                 // h(-1) = 0
  }
  const float ebv = eb[0];
  unsigned ep = 0;

  for (int t = 0; t < TT; ++t) {
    float* xc = (t & 1) ? xkT1 : xkT0;   // ctx(t) rows 0..511, h(t-1) rows 512..767
    float* xn = (t & 1) ? xkT0 : xkT1;   // h(t) written to rows 512..767

    // ---------------- Phase A: dp + attention + softmax + context ------------
    __syncthreads();
    if (tid < 256) {
      float acc = dlb[tid];
      const float* dw = DW2 + tid;
#pragma unroll 8
      for (int k = 0; k < DECH; ++k) acc += dw[k * 256] * h_s[k];
      dp_s[tid] = acc;
    }
    __syncthreads();
    {
      int q = tid & 63, pt = tid >> 6;
      const float* weB = we + ((size_t)b << 16);
      float s0 = 0, s1 = 0, s2 = 0, s3 = 0;
      int abase = pt * 32;
#pragma unroll 4
      for (int i = 0; i < 32; ++i) {
        int aa = abase + i;
        float4 wv = *(const float4*)(weB + (size_t)aa * 256 + q * 4);
        float d = dp_s[aa], w8 = ew_s[aa];
        s0 += w8 * ftanh(wv.x + d);
        s1 += w8 * ftanh(wv.y + d);
        s2 += w8 * ftanh(wv.z + d);
        s3 += w8 * ftanh(wv.w + d);
      }
      partA[pt][q][0] = s0; partA[pt][q][1] = s1;
      partA[pt][q][2] = s2; partA[pt][q][3] = s3;
    }
    __syncthreads();
    float sv = 0.0f;
    if (tid < 256) {
      sv = ebv;
#pragma unroll
      for (int p = 0; p < 8; ++p) sv += partA[p][tid >> 2][tid & 3];
      float mm = sv;
      for (int off = 32; off; off >>= 1) mm = fmaxf(mm, __shfl_xor(mm, off));
      if ((tid & 63) == 0) red[tid >> 6] = mm;
    }
    __syncthreads();
    float mA = fmaxf(fmaxf(red[0], red[1]), fmaxf(red[2], red[3]));
    float pa = 0.0f;
    if (tid < 256) {
      pa = expf(sv - mA);
      float ss = pa;
      for (int off = 32; off; off >>= 1) ss += __shfl_xor(ss, off);
      if ((tid & 63) == 0) red[4 + (tid >> 6)] = ss;
    }
    __syncthreads();
    {
      float S = red[4] + red[5] + red[6] + red[7];
      if (tid < 256) {
        float alpha = pa / S;
        sc_s[tid] = alpha;
        out[(size_t)(BATCH * TT * VOC) + (size_t)(BATCH * TT) +
            ((size_t)b * TT + t) * WWID + tid] = alpha;
      }
    }
    __syncthreads();
    {
      int lane = tid & 63, wvi = tid >> 6;
      const float* encB = enc + (size_t)b * ENCH * WWID;
      float4 al = *(const float4*)&sc_s[lane * 4];
#pragma unroll 2
      for (int e = wvi; e < ENCH; e += 8) {
        float4 evv = *(const float4*)(encB + (size_t)e * WWID + lane * 4);
        float s = evv.x * al.x + evv.y * al.y + evv.z * al.z + evv.w * al.w;
        for (int off = 32; off; off >>= 1) s += __shfl_xor(s, off);
        if (lane == 0)
          __hip_atomic_store(&xc[(size_t)e * 256 + b], s, RLX, AGENT);
      }
    }
    ++ep; gbar(cnt, ep * 256u);

    // ---------------- Phase B: gates GEMM (K=768, ks 8x96) + LSTM ------------
    // stage x-block (768 rows x 16 batches) into LDS via agent-scope atomics
    {
      if (tid < 16) x_s[tid] = __hip_atomic_load(&xbuf[b0 + tid], RLX, AGENT);
      unsigned long long* xl8 = (unsigned long long*)blob;
#pragma unroll
      for (int p = 0; p < 12; ++p) {
        int g = p * 512 + tid;            // u64 index over [768][16] floats
        int k = g >> 3, bp = g & 7;       // bp = pair of batches
        const unsigned long long* src =
            (const unsigned long long*)(xc + (size_t)k * 256 + b0) + bp;
        xl8[g] = __hip_atomic_load(src, RLX, AGENT);
      }
    }
    __syncthreads();
    float acc[16] = {};
    {
      int ks = tid >> 6, r = tid & 63;
      int col = (jt << 6) + r;
      int k0 = ks * 96;
      for (int k = k0; k < k0 + 96; ++k) {
        float wv = W2[(size_t)k * 1024 + col];
        const float4* xp = (const float4*)(blob + (k << 4));
        float4 a0 = xp[0], a1 = xp[1], a2 = xp[2], a3 = xp[3];
        acc[0] += wv * a0.x; acc[1] += wv * a0.y; acc[2] += wv * a0.z; acc[3] += wv * a0.w;
        acc[4] += wv * a1.x; acc[5] += wv * a1.y; acc[6] += wv * a1.z; acc[7] += wv * a1.w;
        acc[8] += wv * a2.x; acc[9] += wv * a2.y; acc[10] += wv * a2.z; acc[11] += wv * a2.w;
        acc[12] += wv * a3.x; acc[13] += wv * a3.y; acc[14] += wv * a3.z; acc[15] += wv * a3.w;
      }
    }
    __syncthreads();   // x_lds dead; blob becomes partB
    {
      int ks = tid >> 6, r = tid & 63;
#pragma unroll
      for (int bi = 0; bi < 16; ++bi) partB[ks][r][bi] = acc[bi];
    }
    __syncthreads();
    if (tid < 256) {
      int bb = tid >> 4, jj = tid & 15;
      float g4[4];
#pragma unroll
      for (int g = 0; g < 4; ++g) {
        int rr = (g << 4) + jj;
        float s = 0.0f;
#pragma unroll
        for (int p = 0; p < 8; ++p) s += partB[p][rr][bb];
        g4[g] = s;
      }
      const float* er = embg + (size_t)x_s[bb] * 1024 + (jt << 6) + jj;
      float iv = fsig(g4[0] + er[0]);
      float fv = fsig(g4[1] + er[16]);
      float gv = ftanh(g4[2] + er[32]);
      float ov = fsig(g4[3] + er[48]);
      int gb = b0 + bb, j = (jt << 4) + jj;
      int cidx = gb * 256 + j;
      float cn = fv * cbuf[cidx] + iv * gv;   // cbuf: same thread every step
      float hn = ov * ftanh(cn);
      cbuf[cidx] = cn;
      __hip_atomic_store(&hbuf[cidx], hn, RLX, AGENT);
      __hip_atomic_store(&xn[(size_t)(512 + j) * 256 + gb], hn, RLX, AGENT);
    }
    ++ep; gbar(cnt, ep * 256u);

    // ---------------- Phase C: logits + log_softmax + argmax -----------------
    if (tid < 256)
      h_s[tid] = __hip_atomic_load(&hbuf[b * 256 + tid], RLX, AGENT);
    __syncthreads();
    {
      int lane = tid & 63, wv = tid >> 6;
      float4 hh = *(const float4*)&h_s[lane * 4];
      for (int v = wv; v < VOC; v += 8) {
        float4 wr = *(const float4*)(ow + (size_t)v * 256 + lane * 4);
        float s = wr.x * hh.x + wr.y * hh.y + wr.z * hh.z + wr.w * hh.w;
        for (int off = 32; off; off >>= 1) s += __shfl_xor(s, off);
        if (lane == 0) lg[v] = s + ob[v];
      }
    }
    __syncthreads();
    float v_ = -3.402823e38f, pe = 0.0f;
    if (tid < 256) {
      v_ = (tid < VOC) ? lg[tid] : -3.402823e38f;
      float mm = v_;
      for (int off = 32; off; off >>= 1) mm = fmaxf(mm, __shfl_xor(mm, off));
      if ((tid & 63) == 0) red[tid >> 6] = mm;
    }
    __syncthreads();
    float mC = fmaxf(fmaxf(red[0], red[1]), fmaxf(red[2], red[3]));
    if (tid < 256) {
      pe = (tid < VOC) ? expf(v_ - mC) : 0.0f;
      float ss = pe;
      for (int off = 32; off; off >>= 1) ss += __shfl_xor(ss, off);
      if ((tid & 63) == 0) red[4 + (tid >> 6)] = ss;
    }
    __syncthreads();
    {
      float S = red[4] + red[5] + red[6] + red[7];
      float lse = mC + logf(S);
      if (tid < VOC) {
        float lp = v_ - lse;
        lp_s[tid] = lp;
        out[((size_t)b * TT + t) * VOC + tid] = lp;
      }
    }
    __syncthreads();
    if (tid == 0) {
      int best = 0;
      float bv = lp_s[0];
      for (int v = 1; v < VOC; ++v) {
        float x = lp_s[v];
        if (x > bv) { bv = x; best = v; }
      }
      __hip_atomic_store(&xbuf[b], best, RLX, AGENT);
      out[(size_t)(BATCH * TT * VOC) + (size_t)b * TT + t] = (float)best;
    }
    // no barrier here: xbuf(t) is read by B(t+1) only after the A(t+1) barrier
  }
}

extern "C" void kernel_launch(void* const* d_in, const int* in_sizes, int n_in,
                              void* d_out, int out_size, void* d_ws, size_t ws_size,
                              hipStream_t stream) {
  (void)in_sizes; (void)n_in; (void)out_size; (void)ws_size;
  const float* enc = (const float*)d_in[0];
  const float* emb = (const float*)d_in[1];
  const float* ecw = (const float*)d_in[2];
  const float* ecb = (const float*)d_in[3];
  const float* dlw = (const float*)d_in[4];
  const float* dlb = (const float*)d_in[5];
  const float* ew  = (const float*)d_in[6];
  const float* eb  = (const float*)d_in[7];
  const float* wih = (const float*)d_in[8];
  const float* whh = (const float*)d_in[9];
  const float* bih = (const float*)d_in[10];
  const float* bhh = (const float*)d_in[11];
  const float* ow  = (const float*)d_in[12];
  const float* ob  = (const float*)d_in[13];
  const int* sos   = (const int*)d_in[15];
  float* out = (float*)d_out;
  float* ws = (float*)d_ws;

  // workspace map (floats)
  size_t off = 0;
  float* we    = ws + off; off += (size_t)BATCH * ATT * WWID;  // 16,777,216
  float* W2    = ws + off; off += (size_t)768 * 1024;
  float* DW2   = ws + off; off += (size_t)256 * 256;
  float* embg  = ws + off; off += (size_t)VOC * 1024;
  off = (off + 255) & ~(size_t)255;
  float* xkT0  = ws + off; off += (size_t)768 * 256;  // rows 0..511 ctx, 512..767 h
  float* xkT1  = ws + off; off += (size_t)768 * 256;
  float* cbuf  = ws + off; off += (size_t)256 * 256;
  float* hbuf  = ws + off; off += (size_t)256 * 256;
  int* xbuf    = (int*)(ws + off); off += 256;
  unsigned* cnt = (unsigned*)(ws + off); off += 64;

  k_init<<<257, 256, 0, stream>>>(cbuf, xkT0 + (size_t)512 * 256, hbuf, xbuf, cnt, sos);
  k_build<<<1024, 256, 0, stream>>>(wih, whh, dlw, W2, DW2);
  k_embg<<<VOC, 256, 0, stream>>>(emb, wih, bih, bhh, embg);
  k_we<<<4096, 256, 0, stream>>>(enc, ecw, ecb, we);
  k_loop<<<256, 512, 0, stream>>>(we, enc, W2, DW2, embg, dlb, ew, eb, ow, ob,
                                  xkT0, xkT1, cbuf, hbuf, xbuf, cnt, out);
}

// Round 5
// 9488.345 us; speedup vs baseline: 2.0081x; 1.2515x over previous
//
#include <hip/hip_runtime.h>

// Shapes (fixed by the problem)
#define BATCH 256
#define ENCH  512   // encoder hidden (e)
#define WWID  256   // encoder width  (w)
#define ATT   256   // attn size      (a)
#define DECH  256   // decoder hidden (d)
#define EMBD  128
#define VOC   81
#define TT    100

// ---------- numerics: fp32, libm-grade (trajectory must match np fp32 ref) ----
__device__ __forceinline__ float ftanh(float x) {
  float e = expf(2.0f * x);
  return 1.0f - 2.0f / (e + 1.0f);
}
__device__ __forceinline__ float fsig(float x) {
  return 1.0f / (1.0f + expf(-x));
}

// ------------- build transposed weights: W2[k][g], DW2[k][a] -----------------
// W2 rows 0..511 = w_ih ctx part (w_ih[:,128+k]^T), rows 512..767 = w_hh^T.
// Natural gate-major columns g = gate*256 + j.
__global__ void k_build(const float* __restrict__ w_ih, const float* __restrict__ w_hh,
                        const float* __restrict__ dlw,
                        float* __restrict__ W2, float* __restrict__ DW2) {
  int k = blockIdx.x, tid = threadIdx.x;
  if (k < 768) {
    for (int g = tid; g < 1024; g += 256)
      W2[(size_t)k * 1024 + g] = (k < 512) ? w_ih[(size_t)g * 640 + 128 + k]
                                           : w_hh[(size_t)g * 256 + (k - 512)];
  } else {
    int kk = k - 768;
    DW2[kk * 256 + tid] = dlw[tid * 256 + kk];
  }
}

// ---------- emb_gates[v][g] = b_ih[g]+b_hh[g] + sum_e emb[v][e] w_ih[g][e] ---
__global__ void k_embg(const float* __restrict__ emb, const float* __restrict__ w_ih,
                       const float* __restrict__ b_ih, const float* __restrict__ b_hh,
                       float* __restrict__ embg) {
  int v = blockIdx.x, tid = threadIdx.x;
  __shared__ float em[EMBD];
  if (tid < EMBD) em[tid] = emb[v * EMBD + tid];
  __syncthreads();
  for (int g = tid; g < 1024; g += 256) {
    float s = b_ih[g] + b_hh[g];
    const float* wr = w_ih + (size_t)g * 640;
#pragma unroll 8
    for (int e = 0; e < EMBD; ++e) s += em[e] * wr[e];
    embg[v * 1024 + g] = s;
  }
}

// ------------- weighted_enc[b][a][w] = sum_e cw[a][e] enc[b][e][w] + cb[a] ----
__global__ void __launch_bounds__(256) k_we(const float* __restrict__ enc,
                                            const float* __restrict__ cw,
                                            const float* __restrict__ cb,
                                            float* __restrict__ we) {
  int bid = blockIdx.x;
  int b = bid >> 4, at = (bid >> 2) & 3, wt = bid & 3;
  int a0 = at * 64, w0 = wt * 64;
  __shared__ float cwT[32][68];
  __shared__ float encT[32][64];
  int tid = threadIdx.x;
  int tx = tid & 15, ty = tid >> 4;
  float acc[4][4] = {};
  const float* encB = enc + (size_t)b * ENCH * WWID;
  for (int k0 = 0; k0 < ENCH; k0 += 32) {
    {
      int a = tid >> 2, e8 = (tid & 3) * 8;
      const float* src = cw + (size_t)(a0 + a) * ENCH + k0 + e8;
      float4 v0 = *(const float4*)(src);
      float4 v1 = *(const float4*)(src + 4);
      cwT[e8 + 0][a] = v0.x; cwT[e8 + 1][a] = v0.y; cwT[e8 + 2][a] = v0.z; cwT[e8 + 3][a] = v0.w;
      cwT[e8 + 4][a] = v1.x; cwT[e8 + 5][a] = v1.y; cwT[e8 + 6][a] = v1.z; cwT[e8 + 7][a] = v1.w;
    }
    {
      int e = tid >> 3, w8 = (tid & 7) * 8;
      const float* src = encB + (size_t)(k0 + e) * WWID + w0 + w8;
      *(float4*)&encT[e][w8] = *(const float4*)src;
      *(float4*)&encT[e][w8 + 4] = *(const float4*)(src + 4);
    }
    __syncthreads();
#pragma unroll
    for (int e = 0; e < 32; ++e) {
      float4 av = *(const float4*)&cwT[e][ty * 4];
      float4 bv = *(const float4*)&encT[e][tx * 4];
      float a4[4] = {av.x, av.y, av.z, av.w};
      float b4[4] = {bv.x, bv.y, bv.z, bv.w};
#pragma unroll
      for (int i = 0; i < 4; ++i)
#pragma unroll
        for (int j = 0; j < 4; ++j) acc[i][j] += a4[i] * b4[j];
    }
    __syncthreads();
  }
#pragma unroll
  for (int i = 0; i < 4; ++i) {
    int a = a0 + ty * 4 + i;
    float bias = cb[a];
    float4 o;
    o.x = acc[i][0] + bias; o.y = acc[i][1] + bias;
    o.z = acc[i][2] + bias; o.w = acc[i][3] + bias;
    *(float4*)(we + ((size_t)(b * ATT + a)) * WWID + w0 + tx * 4) = o;
  }
}

// =============== persistent per-batch kernel: all 100 steps ==================
// grid 256 blocks (one per batch) x 512 threads. NO grid barriers, NO atomics:
// the recurrence is per-batch independent; h/c/x/ctx live in LDS. Weights
// (W2 3MB, DW2 0.25MB, embg 0.33MB, ow) stay L2-resident per XCD; we/enc
// stream from L3. Blocks free-run -> phases overlap chip-wide.
__global__ void __launch_bounds__(512, 1) k_loop(
    const float* __restrict__ we, const float* __restrict__ enc,
    const float* __restrict__ W2, const float* __restrict__ DW2,
    const float* __restrict__ embg, const float* __restrict__ dlb,
    const float* __restrict__ ew, const float* __restrict__ eb,
    const float* __restrict__ ow, const float* __restrict__ ob,
    const int* __restrict__ sos, float* __restrict__ out) {
  const int tid = threadIdx.x;
  const int b = blockIdx.x;

  __shared__ float xf_s[768];              // x = [ctx(0..511) | h(512..767)]
  __shared__ float c_s[256];
  __shared__ float dp_s[256], ew_s[256], sc_s[256];
  __shared__ float partA[8][64][4];
  __shared__ float red[8];
  __shared__ float rF[256], rO[256];
  __shared__ float lg[VOC], lp_s[VOC];
  __shared__ int xcur;

  if (tid < 256) {
    ew_s[tid] = ew[tid];
    c_s[tid] = 0.0f;
    xf_s[512 + tid] = 0.0f;                // h(-1) = 0
  }
  if (tid == 0) xcur = sos[0];
  const float ebv = eb[0];
  const float* weB = we + ((size_t)b << 16);
  const float* encB = enc + (size_t)b * ENCH * WWID;
  __syncthreads();

  for (int t = 0; t < TT; ++t) {
    // ---------- dp[a] = dlb[a] + sum_k h[k] * DW2[k][a] ----------------------
    if (tid < 256) {
      float acc = dlb[tid];
      const float* dw = DW2 + tid;
#pragma unroll 8
      for (int k = 0; k < DECH; ++k) acc += dw[k * 256] * xf_s[512 + k];
      dp_s[tid] = acc;
    }
    __syncthreads();
    // ---------- scores: sum_a ew[a] * tanh(we[a][w] + dp[a]) -----------------
    {
      int q = tid & 63, pt = tid >> 6;
      float s0 = 0, s1 = 0, s2 = 0, s3 = 0;
      int abase = pt * 32;
#pragma unroll 8
      for (int i = 0; i < 32; ++i) {
        int aa = abase + i;
        float4 wv = *(const float4*)(weB + (size_t)aa * 256 + q * 4);
        float d = dp_s[aa], w8 = ew_s[aa];
        s0 += w8 * ftanh(wv.x + d);
        s1 += w8 * ftanh(wv.y + d);
        s2 += w8 * ftanh(wv.z + d);
        s3 += w8 * ftanh(wv.w + d);
      }
      partA[pt][q][0] = s0; partA[pt][q][1] = s1;
      partA[pt][q][2] = s2; partA[pt][q][3] = s3;
    }
    __syncthreads();
    // ---------- softmax over w (256) -----------------------------------------
    float sv = 0.0f;
    if (tid < 256) {
      sv = ebv;
#pragma unroll
      for (int p = 0; p < 8; ++p) sv += partA[p][tid >> 2][tid & 3];
      float mm = sv;
      for (int off = 32; off; off >>= 1) mm = fmaxf(mm, __shfl_xor(mm, off));
      if ((tid & 63) == 0) red[tid >> 6] = mm;
    }
    __syncthreads();
    float mA = fmaxf(fmaxf(red[0], red[1]), fmaxf(red[2], red[3]));
    float pa = 0.0f;
    if (tid < 256) {
      pa = expf(sv - mA);
      float ss = pa;
      for (int off = 32; off; off >>= 1) ss += __shfl_xor(ss, off);
      if ((tid & 63) == 0) red[4 + (tid >> 6)] = ss;
    }
    __syncthreads();
    {
      float S = red[4] + red[5] + red[6] + red[7];
      if (tid < 256) {
        float alpha = pa / S;
        sc_s[tid] = alpha;
        out[(size_t)(BATCH * TT * VOC) + (size_t)(BATCH * TT) +
            ((size_t)b * TT + t) * WWID + tid] = alpha;
      }
    }
    __syncthreads();
    // ---------- context[e] = sum_w enc[b][e][w] * alpha[w]  -> xf_s[e] -------
    {
      int lane = tid & 63, wvi = tid >> 6;
      float4 al = *(const float4*)&sc_s[lane * 4];
#pragma unroll 2
      for (int e = wvi; e < ENCH; e += 8) {
        float4 evv = *(const float4*)(encB + (size_t)e * WWID + lane * 4);
        float s = evv.x * al.x + evv.y * al.y + evv.z * al.z + evv.w * al.w;
        for (int off = 32; off; off >>= 1) s += __shfl_xor(s, off);
        if (lane == 0) xf_s[e] = s;
      }
    }
    __syncthreads();
    // ---------- gates GEMV: cols {tid, tid+512}, K = 768 ---------------------
    float acc1 = 0.0f, acc2 = 0.0f;
    {
      const float* w0 = W2 + tid;
#pragma unroll 4
      for (int k4 = 0; k4 < 192; ++k4) {
        float4 xv = *(const float4*)&xf_s[k4 * 4];
        const float* wp = w0 + (size_t)k4 * 4096;
        acc1 += wp[0] * xv.x + wp[1024] * xv.y + wp[2048] * xv.z + wp[3072] * xv.w;
        acc2 += wp[512] * xv.x + wp[1536] * xv.y + wp[2560] * xv.z + wp[3584] * xv.w;
      }
    }
    {
      int xc_ = xcur;
      float e1 = embg[(size_t)xc_ * 1024 + tid];
      float e2 = embg[(size_t)xc_ * 1024 + 512 + tid];
      if (tid >= 256) {                     // f and o pre-activations
        rF[tid - 256] = acc1 + e1;
        rO[tid - 256] = acc2 + e2;
      }
      __syncthreads();
      if (tid < 256) {                      // i, g + LSTM cell
        float iv = fsig(acc1 + e1);
        float gv = ftanh(acc2 + e2);
        float fv = fsig(rF[tid]);
        float ov = fsig(rO[tid]);
        float cn = fv * c_s[tid] + iv * gv;
        float hn = ov * ftanh(cn);
        c_s[tid] = cn;
        xf_s[512 + tid] = hn;               // h(t)
      }
    }
    __syncthreads();
    // ---------- logits + log_softmax + argmax --------------------------------
    {
      int lane = tid & 63, wv = tid >> 6;
      float4 hh = *(const float4*)&xf_s[512 + lane * 4];
      for (int v = wv; v < VOC; v += 8) {
        float4 wr = *(const float4*)(ow + (size_t)v * 256 + lane * 4);
        float s = wr.x * hh.x + wr.y * hh.y + wr.z * hh.z + wr.w * hh.w;
        for (int off = 32; off; off >>= 1) s += __shfl_xor(s, off);
        if (lane == 0) lg[v] = s + ob[v];
      }
    }
    __syncthreads();
    float v_ = -3.402823e38f, pe = 0.0f;
    if (tid < 256) {
      v_ = (tid < VOC) ? lg[tid] : -3.402823e38f;
      float mm = v_;
      for (int off = 32; off; off >>= 1) mm = fmaxf(mm, __shfl_xor(mm, off));
      if ((tid & 63) == 0) red[tid >> 6] = mm;
    }
    __syncthreads();
    float mC = fmaxf(fmaxf(red[0], red[1]), fmaxf(red[2], red[3]));
    if (tid < 256) {
      pe = (tid < VOC) ? expf(v_ - mC) : 0.0f;
      float ss = pe;
      for (int off = 32; off; off >>= 1) ss += __shfl_xor(ss, off);
      if ((tid & 63) == 0) red[4 + (tid >> 6)] = ss;
    }
    __syncthreads();
    {
      float S = red[4] + red[5] + red[6] + red[7];
      float lse = mC + logf(S);
      if (tid < VOC) {
        float lp = v_ - lse;
        lp_s[tid] = lp;
        out[((size_t)b * TT + t) * VOC + tid] = lp;
      }
    }
    __syncthreads();
    if (tid == 0) {
      int best = 0;
      float bv = lp_s[0];
      for (int v = 1; v < VOC; ++v) {
        float x = lp_s[v];
        if (x > bv) { bv = x; best = v; }
      }
      xcur = best;
      out[(size_t)(BATCH * TT * VOC) + (size_t)b * TT + t] = (float)best;
    }
    __syncthreads();
  }
}

extern "C" void kernel_launch(void* const* d_in, const int* in_sizes, int n_in,
                              void* d_out, int out_size, void* d_ws, size_t ws_size,
                              hipStream_t stream) {
  (void)in_sizes; (void)n_in; (void)out_size; (void)ws_size;
  const float* enc = (const float*)d_in[0];
  const float* emb = (const float*)d_in[1];
  const float* ecw = (const float*)d_in[2];
  const float* ecb = (const float*)d_in[3];
  const float* dlw = (const float*)d_in[4];
  const float* dlb = (const float*)d_in[5];
  const float* ew  = (const float*)d_in[6];
  const float* eb  = (const float*)d_in[7];
  const float* wih = (const float*)d_in[8];
  const float* whh = (const float*)d_in[9];
  const float* bih = (const float*)d_in[10];
  const float* bhh = (const float*)d_in[11];
  const float* ow  = (const float*)d_in[12];
  const float* ob  = (const float*)d_in[13];
  const int* sos   = (const int*)d_in[15];
  float* out = (float*)d_out;
  float* ws = (float*)d_ws;

  // workspace map (floats); ~17.7M floats ~ 71 MB
  size_t off = 0;
  float* we    = ws + off; off += (size_t)BATCH * ATT * WWID;  // 16,777,216
  float* W2    = ws + off; off += (size_t)768 * 1024;
  float* DW2   = ws + off; off += (size_t)256 * 256;
  float* embg  = ws + off; off += (size_t)VOC * 1024;

  k_build<<<1024, 256, 0, stream>>>(wih, whh, dlw, W2, DW2);
  k_embg<<<VOC, 256, 0, stream>>>(emb, wih, bih, bhh, embg);
  k_we<<<4096, 256, 0, stream>>>(enc, ecw, ecb, we);
  k_loop<<<256, 512, 0, stream>>>(we, enc, W2, DW2, embg, dlb, ew, eb, ow, ob,
                                  sos, out);
}

// Round 6
// 8780.739 us; speedup vs baseline: 2.1699x; 1.0806x over previous
//
#include <hip/hip_runtime.h>

// Shapes (fixed by the problem)
#define BATCH 256
#define ENCH  512   // encoder hidden (e)
#define WWID  256   // encoder width  (w)
#define ATT   256   // attn size      (a)
#define DECH  256   // decoder hidden (d)
#define EMBD  128
#define VOC   81
#define TT    100

// ---------- numerics: fp32, libm-grade (trajectory must match np fp32 ref) ----
__device__ __forceinline__ float ftanh(float x) {
  float e = expf(2.0f * x);
  return 1.0f - 2.0f / (e + 1.0f);
}
__device__ __forceinline__ float fsig(float x) {
  return 1.0f / (1.0f + expf(-x));
}

// ------------- build transposed weights: W2[k][g], DW2[k][a] -----------------
// W2 rows 0..511 = w_ih ctx part (w_ih[:,128+k]^T), rows 512..767 = w_hh^T.
// Natural gate-major columns g = gate*256 + j.
__global__ void k_build(const float* __restrict__ w_ih, const float* __restrict__ w_hh,
                        const float* __restrict__ dlw,
                        float* __restrict__ W2, float* __restrict__ DW2) {
  int k = blockIdx.x, tid = threadIdx.x;
  if (k < 768) {
    for (int g = tid; g < 1024; g += 256)
      W2[(size_t)k * 1024 + g] = (k < 512) ? w_ih[(size_t)g * 640 + 128 + k]
                                           : w_hh[(size_t)g * 256 + (k - 512)];
  } else {
    int kk = k - 768;
    DW2[kk * 256 + tid] = dlw[tid * 256 + kk];
  }
}

// ---------- emb_gates[v][g] = b_ih[g]+b_hh[g] + sum_e emb[v][e] w_ih[g][e] ---
__global__ void k_embg(const float* __restrict__ emb, const float* __restrict__ w_ih,
                       const float* __restrict__ b_ih, const float* __restrict__ b_hh,
                       float* __restrict__ embg) {
  int v = blockIdx.x, tid = threadIdx.x;
  __shared__ float em[EMBD];
  if (tid < EMBD) em[tid] = emb[v * EMBD + tid];
  __syncthreads();
  for (int g = tid; g < 1024; g += 256) {
    float s = b_ih[g] + b_hh[g];
    const float* wr = w_ih + (size_t)g * 640;
#pragma unroll 8
    for (int e = 0; e < EMBD; ++e) s += em[e] * wr[e];
    embg[v * 1024 + g] = s;
  }
}

// ------------- weighted_enc[b][a][w] = sum_e cw[a][e] enc[b][e][w] + cb[a] ----
__global__ void __launch_bounds__(256) k_we(const float* __restrict__ enc,
                                            const float* __restrict__ cw,
                                            const float* __restrict__ cb,
                                            float* __restrict__ we) {
  int bid = blockIdx.x;
  int b = bid >> 4, at = (bid >> 2) & 3, wt = bid & 3;
  int a0 = at * 64, w0 = wt * 64;
  __shared__ float cwT[32][68];
  __shared__ float encT[32][64];
  int tid = threadIdx.x;
  int tx = tid & 15, ty = tid >> 4;
  float acc[4][4] = {};
  const float* encB = enc + (size_t)b * ENCH * WWID;
  for (int k0 = 0; k0 < ENCH; k0 += 32) {
    {
      int a = tid >> 2, e8 = (tid & 3) * 8;
      const float* src = cw + (size_t)(a0 + a) * ENCH + k0 + e8;
      float4 v0 = *(const float4*)(src);
      float4 v1 = *(const float4*)(src + 4);
      cwT[e8 + 0][a] = v0.x; cwT[e8 + 1][a] = v0.y; cwT[e8 + 2][a] = v0.z; cwT[e8 + 3][a] = v0.w;
      cwT[e8 + 4][a] = v1.x; cwT[e8 + 5][a] = v1.y; cwT[e8 + 6][a] = v1.z; cwT[e8 + 7][a] = v1.w;
    }
    {
      int e = tid >> 3, w8 = (tid & 7) * 8;
      const float* src = encB + (size_t)(k0 + e) * WWID + w0 + w8;
      *(float4*)&encT[e][w8] = *(const float4*)src;
      *(float4*)&encT[e][w8 + 4] = *(const float4*)(src + 4);
    }
    __syncthreads();
#pragma unroll
    for (int e = 0; e < 32; ++e) {
      float4 av = *(const float4*)&cwT[e][ty * 4];
      float4 bv = *(const float4*)&encT[e][tx * 4];
      float a4[4] = {av.x, av.y, av.z, av.w};
      float b4[4] = {bv.x, bv.y, bv.z, bv.w};
#pragma unroll
      for (int i = 0; i < 4; ++i)
#pragma unroll
        for (int j = 0; j < 4; ++j) acc[i][j] += a4[i] * b4[j];
    }
    __syncthreads();
  }
#pragma unroll
  for (int i = 0; i < 4; ++i) {
    int a = a0 + ty * 4 + i;
    float bias = cb[a];
    float4 o;
    o.x = acc[i][0] + bias; o.y = acc[i][1] + bias;
    o.z = acc[i][2] + bias; o.w = acc[i][3] + bias;
    *(float4*)(we + ((size_t)(b * ATT + a)) * WWID + w0 + tx * 4) = o;
  }
}

// =============== persistent per-batch kernel: all 100 steps ==================
// grid 256 blocks (one per batch) x 1024 threads (16 waves/CU for latency
// hiding). NO grid barriers, NO atomics: recurrence is per-batch independent;
// h/c/x/ctx live in LDS. W2/DW2/embg/ow are L2-resident per XCD; we/enc
// stream from L3. Blocks free-run -> phases overlap chip-wide.
__global__ void __launch_bounds__(1024, 1) k_loop(
    const float* __restrict__ we, const float* __restrict__ enc,
    const float* __restrict__ W2, const float* __restrict__ DW2,
    const float* __restrict__ embg, const float* __restrict__ dlb,
    const float* __restrict__ ew, const float* __restrict__ eb,
    const float* __restrict__ ow, const float* __restrict__ ob,
    const int* __restrict__ sos, float* __restrict__ out) {
  const int tid = threadIdx.x;
  const int b = blockIdx.x;

  __shared__ float xf_s[768];              // x = [ctx(0..511) | h(512..767)]
  __shared__ float c_s[256];
  __shared__ float dp_s[256], ew_s[256], sc_s[256];
  __shared__ float partA[16][64][4];       // 16 KB
  __shared__ float gpre_s[1024];
  __shared__ float red[8];
  __shared__ float lg[VOC], lp_s[VOC];
  __shared__ int xcur;

  if (tid < 256) {
    ew_s[tid] = ew[tid];
    c_s[tid] = 0.0f;
    xf_s[512 + tid] = 0.0f;                // h(-1) = 0
  }
  if (tid == 0) xcur = sos[0];
  const float ebv = eb[0];
  const float* weB = we + ((size_t)b << 16);
  const float* encB = enc + (size_t)b * ENCH * WWID;
  __syncthreads();

  for (int t = 0; t < TT; ++t) {
    // ---------- dp[a] = dlb[a] + sum_k h[k] * DW2[k][a]  (exact r5 order) ----
    if (tid < 256) {
      float acc = dlb[tid];
      const float* dw = DW2 + tid;
#pragma unroll 8
      for (int k = 0; k < DECH; ++k) acc += dw[k * 256] * xf_s[512 + k];
      dp_s[tid] = acc;
    }
    __syncthreads();
    // ---------- scores: 16 waves x 16 a-rows each ----------------------------
    {
      int q = tid & 63, pt = tid >> 6;
      float s0 = 0, s1 = 0, s2 = 0, s3 = 0;
      int abase = pt * 16;
#pragma unroll 4
      for (int i = 0; i < 16; ++i) {
        int aa = abase + i;
        float4 wv = *(const float4*)(weB + (size_t)aa * 256 + q * 4);
        float d = dp_s[aa], w8 = ew_s[aa];
        s0 += w8 * ftanh(wv.x + d);
        s1 += w8 * ftanh(wv.y + d);
        s2 += w8 * ftanh(wv.z + d);
        s3 += w8 * ftanh(wv.w + d);
      }
      partA[pt][q][0] = s0; partA[pt][q][1] = s1;
      partA[pt][q][2] = s2; partA[pt][q][3] = s3;
    }
    __syncthreads();
    // ---------- softmax over w (256) -----------------------------------------
    float sv = 0.0f;
    if (tid < 256) {
      sv = ebv;
#pragma unroll
      for (int p = 0; p < 16; ++p) sv += partA[p][tid >> 2][tid & 3];
      float mm = sv;
      for (int off = 32; off; off >>= 1) mm = fmaxf(mm, __shfl_xor(mm, off));
      if ((tid & 63) == 0) red[tid >> 6] = mm;
    }
    __syncthreads();
    float mA = fmaxf(fmaxf(red[0], red[1]), fmaxf(red[2], red[3]));
    float pa = 0.0f;
    if (tid < 256) {
      pa = expf(sv - mA);
      float ss = pa;
      for (int off = 32; off; off >>= 1) ss += __shfl_xor(ss, off);
      if ((tid & 63) == 0) red[4 + (tid >> 6)] = ss;
    }
    __syncthreads();
    {
      float S = red[4] + red[5] + red[6] + red[7];
      if (tid < 256) {
        float alpha = pa / S;
        sc_s[tid] = alpha;
        out[(size_t)(BATCH * TT * VOC) + (size_t)(BATCH * TT) +
            ((size_t)b * TT + t) * WWID + tid] = alpha;
      }
    }
    __syncthreads();
    // ---------- context[e] = sum_w enc[b][e][w] * alpha[w]  -> xf_s[e] -------
    {
      int lane = tid & 63, wvi = tid >> 6;
      float4 al = *(const float4*)&sc_s[lane * 4];
#pragma unroll 4
      for (int e = wvi; e < ENCH; e += 16) {
        float4 evv = *(const float4*)(encB + (size_t)e * WWID + lane * 4);
        float s = evv.x * al.x + evv.y * al.y + evv.z * al.z + evv.w * al.w;
        for (int off = 32; off; off >>= 1) s += __shfl_xor(s, off);
        if (lane == 0) xf_s[e] = s;
      }
    }
    __syncthreads();
    // ---------- gates GEMV: one thread per column g, K = 768 sequential ------
    {
      float acc = 0.0f;
      const float* w0 = W2 + tid;
#pragma unroll 2
      for (int k4 = 0; k4 < 192; ++k4) {
        float4 xv = *(const float4*)&xf_s[k4 * 4];
        const float* wp = w0 + (size_t)k4 * 4096;
        acc += wp[0] * xv.x + wp[1024] * xv.y + wp[2048] * xv.z + wp[3072] * xv.w;
      }
      gpre_s[tid] = acc + embg[(size_t)xcur * 1024 + tid];
    }
    __syncthreads();
    // ---------- LSTM cell (values bit-identical to r5) -----------------------
    if (tid < 256) {
      float iv = fsig(gpre_s[tid]);
      float fv = fsig(gpre_s[256 + tid]);
      float gv = ftanh(gpre_s[512 + tid]);
      float ov = fsig(gpre_s[768 + tid]);
      float cn = fv * c_s[tid] + iv * gv;
      float hn = ov * ftanh(cn);
      c_s[tid] = cn;
      xf_s[512 + tid] = hn;               // h(t)
    }
    __syncthreads();
    // ---------- logits + log_softmax + argmax --------------------------------
    {
      int lane = tid & 63, wv = tid >> 6;
      float4 hh = *(const float4*)&xf_s[512 + lane * 4];
      for (int v = wv; v < VOC; v += 16) {
        float4 wr = *(const float4*)(ow + (size_t)v * 256 + lane * 4);
        float s = wr.x * hh.x + wr.y * hh.y + wr.z * hh.z + wr.w * hh.w;
        for (int off = 32; off; off >>= 1) s += __shfl_xor(s, off);
        if (lane == 0) lg[v] = s + ob[v];
      }
    }
    __syncthreads();
    float v_ = -3.402823e38f, pe = 0.0f;
    if (tid < 256) {
      v_ = (tid < VOC) ? lg[tid] : -3.402823e38f;
      float mm = v_;
      for (int off = 32; off; off >>= 1) mm = fmaxf(mm, __shfl_xor(mm, off));
      if ((tid & 63) == 0) red[tid >> 6] = mm;
    }
    __syncthreads();
    float mC = fmaxf(fmaxf(red[0], red[1]), fmaxf(red[2], red[3]));
    if (tid < 256) {
      pe = (tid < VOC) ? expf(v_ - mC) : 0.0f;
      float ss = pe;
      for (int off = 32; off; off >>= 1) ss += __shfl_xor(ss, off);
      if ((tid & 63) == 0) red[4 + (tid >> 6)] = ss;
    }
    __syncthreads();
    {
      float S = red[4] + red[5] + red[6] + red[7];
      float lse = mC + logf(S);
      if (tid < VOC) {
        float lp = v_ - lse;
        lp_s[tid] = lp;
        out[((size_t)b * TT + t) * VOC + tid] = lp;
      }
    }
    __syncthreads();
    if (tid == 0) {
      int best = 0;
      float bv = lp_s[0];
      for (int v = 1; v < VOC; ++v) {
        float x = lp_s[v];
        if (x > bv) { bv = x; best = v; }
      }
      xcur = best;
      out[(size_t)(BATCH * TT * VOC) + (size_t)b * TT + t] = (float)best;
    }
    __syncthreads();
  }
}

extern "C" void kernel_launch(void* const* d_in, const int* in_sizes, int n_in,
                              void* d_out, int out_size, void* d_ws, size_t ws_size,
                              hipStream_t stream) {
  (void)in_sizes; (void)n_in; (void)out_size; (void)ws_size;
  const float* enc = (const float*)d_in[0];
  const float* emb = (const float*)d_in[1];
  const float* ecw = (const float*)d_in[2];
  const float* ecb = (const float*)d_in[3];
  const float* dlw = (const float*)d_in[4];
  const float* dlb = (const float*)d_in[5];
  const float* ew  = (const float*)d_in[6];
  const float* eb  = (const float*)d_in[7];
  const float* wih = (const float*)d_in[8];
  const float* whh = (const float*)d_in[9];
  const float* bih = (const float*)d_in[10];
  const float* bhh = (const float*)d_in[11];
  const float* ow  = (const float*)d_in[12];
  const float* ob  = (const float*)d_in[13];
  const int* sos   = (const int*)d_in[15];
  float* out = (float*)d_out;
  float* ws = (float*)d_ws;

  // workspace map (floats); ~17.7M floats ~ 71 MB
  size_t off = 0;
  float* we    = ws + off; off += (size_t)BATCH * ATT * WWID;  // 16,777,216
  float* W2    = ws + off; off += (size_t)768 * 1024;
  float* DW2   = ws + off; off += (size_t)256 * 256;
  float* embg  = ws + off; off += (size_t)VOC * 1024;

  k_build<<<1024, 256, 0, stream>>>(wih, whh, dlw, W2, DW2);
  k_embg<<<VOC, 256, 0, stream>>>(emb, wih, bih, bhh, embg);
  k_we<<<4096, 256, 0, stream>>>(enc, ecw, ecb, we);
  k_loop<<<256, 1024, 0, stream>>>(we, enc, W2, DW2, embg, dlb, ew, eb, ow, ob,
                                   sos, out);
}